// Round 4
// baseline (846.262 us; speedup 1.0000x reference)
//
#include <hip/hip_runtime.h>

typedef _Float16 half8_t __attribute__((ext_vector_type(8)));
typedef _Float16 half4_t __attribute__((ext_vector_type(4)));
typedef _Float16 half2_t __attribute__((ext_vector_type(2)));
typedef float floatx4 __attribute__((ext_vector_type(4)));
typedef float float4_t __attribute__((ext_vector_type(4)));
typedef unsigned int uint4_t __attribute__((ext_vector_type(4)));

__device__ __forceinline__ float sigm_f(float v) {
  return __builtin_amdgcn_rcpf(1.f + __expf(-v));
}
__device__ __forceinline__ float tanh_f(float v) {
  return 2.f * __builtin_amdgcn_rcpf(1.f + __expf(-2.f * v)) - 1.f;
}

// async global->LDS, 16B, NT cache policy (streaming: don't retain in L2)
__device__ __forceinline__ void gl_lds16_nt(const _Float16* g, _Float16* l) {
  __builtin_amdgcn_global_load_lds(
      (const __attribute__((address_space(1))) void*)g,
      (__attribute__((address_space(3))) void*)l, 16, 0, 2 /*NT*/);
}

// ---------------------------------------------------------------------------
// Weight prep: MFMA B-frag order, f16.  col n -> gate=(n>>4)&3,
// hcol=(n>>6)*16+(n&15); oc = gate*128+hcol.  L1 K rows: [0,184)=w_ih,
// [184,192)=0, [192,320)=w_hh.  L2: [0,256)=w_ih, [256,384)=w_hh.
// wswz[dir][kt][ntg=cs*4+nt][lane][8].
// ---------------------------------------------------------------------------
__global__ void prep_kernel(
    const float* __restrict__ wih1f, const float* __restrict__ whh1f,
    const float* __restrict__ bih1f, const float* __restrict__ bhh1f,
    const float* __restrict__ wih1b, const float* __restrict__ whh1b,
    const float* __restrict__ bih1b, const float* __restrict__ bhh1b,
    const float* __restrict__ wih2f, const float* __restrict__ whh2f,
    const float* __restrict__ bih2f, const float* __restrict__ bhh2f,
    const float* __restrict__ wih2b, const float* __restrict__ whh2b,
    const float* __restrict__ bih2b, const float* __restrict__ bhh2b,
    const float* __restrict__ fc1w,
    _Float16* __restrict__ wswz1, _Float16* __restrict__ wswz2,
    _Float16* __restrict__ wfc, float* __restrict__ biasc) {
  const int N1 = 327680, N2 = 393216, NF = 32768, NB = 2048;
  int idx = blockIdx.x * 256 + threadIdx.x;
  if (idx < N1) {
    int d = idx / 163840;
    int r = idx - d * 163840;
    int j = r & 7, lane = (r >> 3) & 63, ntg = (r >> 9) & 31, kt = r >> 14;
    int k = kt * 32 + (lane >> 4) * 8 + j;
    int n = ntg * 16 + (lane & 15);
    int oc = ((n >> 4) & 3) * 128 + (n >> 6) * 16 + (n & 15);
    const float* wih = d ? wih1b : wih1f;
    const float* whh = d ? whh1b : whh1f;
    float v = (k < 184) ? wih[oc * 184 + k]
                        : ((k < 192) ? 0.f : whh[oc * 128 + (k - 192)]);
    wswz1[idx] = (_Float16)v;
  } else if (idx < N1 + N2) {
    int r0 = idx - N1;
    int d = r0 / 196608;
    int r = r0 - d * 196608;
    int j = r & 7, lane = (r >> 3) & 63, ntg = (r >> 9) & 31, kt = r >> 14;
    int k = kt * 32 + (lane >> 4) * 8 + j;
    int n = ntg * 16 + (lane & 15);
    int oc = ((n >> 4) & 3) * 128 + (n >> 6) * 16 + (n & 15);
    const float* wih = d ? wih2b : wih2f;
    const float* whh = d ? whh2b : whh2f;
    float v = (k < 256) ? wih[oc * 256 + k] : whh[oc * 128 + (k - 256)];
    wswz2[r0] = (_Float16)v;
  } else if (idx < N1 + N2 + NF) {
    int r = idx - (N1 + N2);
    int j = r & 7, lane = (r >> 3) & 63, ntg = (r >> 9) & 3, kt = r >> 11;
    int k = kt * 32 + (lane >> 4) * 8 + j;
    int n = ntg * 16 + (lane & 15);
    wfc[r] = (_Float16)fc1w[n * 512 + k];
  } else if (idx < N1 + N2 + NF + NB) {
    int r = idx - (N1 + N2 + NF);
    int n = r & 511, d = (r >> 9) & 1, l = r >> 10;
    int oc = ((n >> 4) & 3) * 128 + (n >> 6) * 16 + (n & 15);
    const float* bi = l ? (d ? bih2b : bih2f) : (d ? bih1b : bih1f);
    const float* bh = l ? (d ? bhh2b : bhh2f) : (d ? bhh1b : bhh1f);
    biasc[r] = bi[oc] + bh[oc];
  }
}

// ---------------------------------------------------------------------------
// LSTM layer v4: 512 thr = 8 waves (one per 64-gate col strip), Mb=128 rows,
// 1 block/CU.  Full-t Xbuf (2 barriers/t), depth-2 W prefetch (bA/bB), NT
// policy on all streaming traffic so weights stay L2-resident.
// LAYER1 stages raw fp32 x (NT load -> f16 -> ds_write, frag order) — xconv
// kernel eliminated.  LAYER2 stages tiled h1out via async global_load_lds NT.
// ---------------------------------------------------------------------------
#define WLOAD(kt, dst)                                                        \
  {                                                                           \
    const _Float16* _p = wd + (((size_t)(kt)*32 + (cs << 2)) * 64 + lane) * 8;\
    _Pragma("unroll") for (int _nt = 0; _nt < 4; ++_nt)                       \
        (dst)[_nt] = *(const half8_t*)(_p + _nt * 512);                       \
  }

#define GEMM_KT(abase, mstride, b)                                            \
  {                                                                           \
    _Pragma("unroll") for (int _mt = 0; _mt < 8; ++_mt) {                     \
      half8_t _a = *(const half8_t*)((abase) + (size_t)_mt * (mstride));      \
      _Pragma("unroll") for (int _nt = 0; _nt < 4; ++_nt)                     \
          acc[_mt][_nt] = __builtin_amdgcn_mfma_f32_16x16x32_f16(             \
              _a, (b)[_nt], acc[_mt][_nt], 0, 0, 0);                          \
    }                                                                         \
  }

template <int LAYER>
__global__ __launch_bounds__(512, 2) void lstm_kernel(
    const void* __restrict__ xin_v, const _Float16* __restrict__ wswz,
    const float* __restrict__ biasc, _Float16* __restrict__ hout) {
  constexpr int XT = (LAYER == 1) ? 6 : 8;  // x k-tiles
  constexpr int KT = XT + 4;
  constexpr int XS = XT * 512;  // Xbuf per-mt stride

  __shared__ __align__(16) _Float16 Hbuf[16384];    // 32 KB, frag order
  __shared__ __align__(16) _Float16 Xbuf[XT * 4096]; // 48/64 KB, frag order

  const int tid = threadIdx.x;
  const int cs = tid >> 6;
  const int lane = tid & 63;
  const int q = lane >> 4;
  const int l15 = lane & 15;
  const int lane8 = lane * 8;
  const int dir = blockIdx.y;
  const int rt0 = blockIdx.x << 3;   // 8 rowtiles = 128 rows per block
  const int row0 = blockIdx.x << 7;

  const _Float16* __restrict__ wd = wswz + (size_t)dir * (KT * 16384);
  const float* __restrict__ bd = biasc + (dir << 9);

  float bias_frag[4];
#pragma unroll
  for (int nt = 0; nt < 4; ++nt) bias_frag[nt] = bd[(cs << 6) + (nt << 4) + l15];

  // stage x_t for time te into Xbuf (full t)
  auto stage = [&](int te) {
    if (LAYER == 1) {
      const float* __restrict__ xf = (const float*)xin_v;
      // 5888 float4 units (128 rows x 46) + 128 pad units
#pragma unroll
      for (int it = 0; it < 12; ++it) {
        int u = tid + it * 512;
        if (u < 5888) {
          int r = u / 46;
          int c = u - r * 46;
          int k0 = c << 2;
          int kt = k0 >> 5, rem = k0 & 31, qq = rem >> 3, j0 = rem & 7;
          float4_t v = __builtin_nontemporal_load(
              (const float4_t*)(xf + (size_t)(row0 + r) * 1840 + te * 184 + k0));
          half4_t hv;
          hv[0] = (_Float16)v[0]; hv[1] = (_Float16)v[1];
          hv[2] = (_Float16)v[2]; hv[3] = (_Float16)v[3];
          *(half4_t*)(Xbuf + (r >> 4) * XS + kt * 512 + qq * 128 + (r & 15) * 8 + j0) = hv;
        } else if (u < 6016) {
          int r = u - 5888;
          half8_t z;
#pragma unroll
          for (int j = 0; j < 8; ++j) z[j] = (_Float16)0.f;
          *(half8_t*)(Xbuf + (r >> 4) * XS + 5 * 512 + 3 * 128 + (r & 15) * 8) = z;
        }
      }
    } else {
      const _Float16* __restrict__ xf = (const _Float16*)xin_v;
      // 8 mt x 8 kt x 64 lanes = 4096 16B-units
#pragma unroll
      for (int it = 0; it < 8; ++it) {
        int u = tid + it * 512;
        int mtile = u >> 9;
        int rem = u & 511;
        gl_lds16_nt(xf + ((size_t)((rt0 + mtile) * 10 + te) * 8) * 512 + rem * 8,
                    Xbuf + mtile * 4096 + rem * 8);
      }
    }
  };

  float c_state[8][4];
#pragma unroll
  for (int mt = 0; mt < 8; ++mt)
#pragma unroll
    for (int rg = 0; rg < 4; ++rg) c_state[mt][rg] = 0.f;

  half8_t bA[4], bB[4];
  WLOAD(0, bA);
  WLOAD(1, bB);
  stage(dir ? 9 : 0);
  // zero Hbuf
  {
    uint4_t z = {0u, 0u, 0u, 0u};
#pragma unroll
    for (int it = 0; it < 4; ++it) *(uint4_t*)(Hbuf + (tid + it * 512) * 8) = z;
  }
  __syncthreads();  // t=0 x staged + Hbuf zeroed

  for (int t = 0; t < 10; ++t) {
    floatx4 acc[8][4];
#pragma unroll
    for (int mt = 0; mt < 8; ++mt)
#pragma unroll
      for (int nt = 0; nt < 4; ++nt) {
        floatx4 b4 = {bias_frag[nt], bias_frag[nt], bias_frag[nt], bias_frag[nt]};
        acc[mt][nt] = b4;
      }

    // ---- full GEMM: x-part (Xbuf) then recurrent (Hbuf), depth-2 W chain
#pragma unroll
    for (int i = 0; i < KT; ++i) {
      const _Float16* abase;
      int mstr;
      if (i < XT) { abase = Xbuf + i * 512 + lane8; mstr = XS; }
      else        { abase = Hbuf + (i - XT) * 512 + lane8; mstr = 2048; }
      half8_t* bu = (i & 1) ? bB : bA;
      GEMM_KT(abase, mstr, bu);
      WLOAD((i + 2) % KT, bu);  // same weights every t -> wrap
    }

    // ---- writeback h(t-1) (NT stores), Hbuf still stable
    if (t > 0) {
      const int t_prev = dir ? (10 - t) : (t - 1);
      if (LAYER == 1) {
#pragma unroll
        for (int it = 0; it < 4; ++it) {
          int j = tid + it * 512;
          uint4_t v = *(const uint4_t*)(Hbuf + j * 8);
          int mt = j >> 8, rem = j & 255;
          __builtin_nontemporal_store(
              v, (uint4_t*)(hout + ((size_t)(((rt0 + mt) * 10 + t_prev) * 8) + (dir << 2)) * 512 +
                            rem * 8));
        }
      } else {
#pragma unroll
        for (int it = 0; it < 4; ++it) {
          int j = tid + it * 512;
          uint4_t v = *(const uint4_t*)(Hbuf + j * 8);
          int rhi = j >> 8, q2 = (j >> 6) & 3, c2 = (j >> 4) & 3, rlo = j & 15;
          __builtin_nontemporal_store(
              v, (uint4_t*)(hout + ((size_t)(row0 + rhi * 16 + rlo) * 10 + t_prev) * 256 +
                            (dir << 7) + (q2 * 4 + c2) * 8));
        }
      }
    }
    __syncthreads();  // all Xbuf/Hbuf reads done

    if (t < 9) stage(dir ? (8 - t) : (t + 1));  // next-t x (hidden under cell)

    // ---- LSTM cell (nt == gate); write h(t) into Hbuf (frag order)
#pragma unroll
    for (int mt = 0; mt < 8; ++mt) {
#pragma unroll
      for (int rg = 0; rg < 4; ++rg) {
        float ig = sigm_f(acc[mt][0][rg]);
        float fg = sigm_f(acc[mt][1][rg]);
        float gg = tanh_f(acc[mt][2][rg]);
        float og = sigm_f(acc[mt][3][rg]);
        float c = fg * c_state[mt][rg] + ig * gg;
        c_state[mt][rg] = c;
        float h = og * tanh_f(c);
        int hoff = (mt * 4 + (cs >> 1)) * 512 +
                   ((((cs & 1) * 2 + (l15 >> 3)) * 16) + (q << 2) + rg) * 8 + (l15 & 7);
        Hbuf[hoff] = (_Float16)h;
      }
    }
    __syncthreads();  // h(t) visible; staged x arrived
  }

  // final writeback h(t=9)
  {
    const int t_last = dir ? 0 : 9;
    if (LAYER == 1) {
#pragma unroll
      for (int it = 0; it < 4; ++it) {
        int j = tid + it * 512;
        uint4_t v = *(const uint4_t*)(Hbuf + j * 8);
        int mt = j >> 8, rem = j & 255;
        __builtin_nontemporal_store(
            v, (uint4_t*)(hout + ((size_t)(((rt0 + mt) * 10 + t_last) * 8) + (dir << 2)) * 512 +
                          rem * 8));
      }
    } else {
#pragma unroll
      for (int it = 0; it < 4; ++it) {
        int j = tid + it * 512;
        uint4_t v = *(const uint4_t*)(Hbuf + j * 8);
        int rhi = j >> 8, q2 = (j >> 6) & 3, c2 = (j >> 4) & 3, rlo = j & 15;
        __builtin_nontemporal_store(
            v, (uint4_t*)(hout + ((size_t)(row0 + rhi * 16 + rlo) * 10 + t_last) * 256 +
                          (dir << 7) + (q2 * 4 + c2) * 8));
      }
    }
  }
}

// ---------------------------------------------------------------------------
// Maxpool (groups of 5 over T) + FC 512->64 relu -> 64->1.
// ---------------------------------------------------------------------------
__global__ __launch_bounds__(256) void fc_kernel(
    const _Float16* __restrict__ h2, const _Float16* __restrict__ wfc,
    const float* __restrict__ fc1b, const float* __restrict__ fc2w,
    const float* __restrict__ fc2b, float* __restrict__ out) {
  __shared__ __align__(16) _Float16 pooled[64 * 520];
  const int tid = threadIdx.x;
  const int s0 = blockIdx.x << 6;

  for (int idx = tid; idx < 64 * 128; idx += 256) {
    int s = idx >> 7;
    int part = idx & 127;
    const _Float16* base = h2 + (size_t)(s0 + s) * 10 * 256 + (part << 1);
    float m00 = -3.4e38f, m01 = -3.4e38f, m10 = -3.4e38f, m11 = -3.4e38f;
#pragma unroll
    for (int t = 0; t < 10; ++t) {
      half2_t hv = *(const half2_t*)(base + t * 256);
      float f0 = (float)hv[0], f1 = (float)hv[1];
      if (t < 5) { m00 = fmaxf(m00, f0); m10 = fmaxf(m10, f1); }
      else       { m01 = fmaxf(m01, f0); m11 = fmaxf(m11, f1); }
    }
    half4_t pv;
    pv[0] = (_Float16)m00; pv[1] = (_Float16)m01;
    pv[2] = (_Float16)m10; pv[3] = (_Float16)m11;
    *(half4_t*)(pooled + s * 520 + (part << 2)) = pv;
  }
  __syncthreads();

  const int wid = tid >> 6, lane = tid & 63, q = lane >> 4, l15 = lane & 15;
  const int m0 = wid << 4;

  const floatx4 fzero = {0.f, 0.f, 0.f, 0.f};
  floatx4 acc[4];
#pragma unroll
  for (int nt = 0; nt < 4; ++nt) acc[nt] = fzero;

#pragma unroll
  for (int kt = 0; kt < 16; ++kt) {
    half8_t a = *(const half8_t*)(pooled + (m0 + l15) * 520 + (kt << 5) + (q << 3));
#pragma unroll
    for (int nt = 0; nt < 4; ++nt) {
      half8_t b = *(const half8_t*)(wfc + ((((size_t)kt << 2) + nt) * 64 + lane) * 8);
      acc[nt] = __builtin_amdgcn_mfma_f32_16x16x32_f16(a, b, acc[nt], 0, 0, 0);
    }
  }

  float b1[4], w2[4];
#pragma unroll
  for (int nt = 0; nt < 4; ++nt) {
    b1[nt] = fc1b[(nt << 4) + l15];
    w2[nt] = fc2w[(nt << 4) + l15];
  }
  const float c2b = fc2b[0];

#pragma unroll
  for (int rg = 0; rg < 4; ++rg) {
    float v = 0.f;
#pragma unroll
    for (int nt = 0; nt < 4; ++nt)
      v += fmaxf(acc[nt][rg] + b1[nt], 0.f) * w2[nt];
    v += __shfl_xor(v, 1, 64);
    v += __shfl_xor(v, 2, 64);
    v += __shfl_xor(v, 4, 64);
    v += __shfl_xor(v, 8, 64);
    if (l15 == 0) out[s0 + m0 + (q << 2) + rg] = v + c2b;
  }
}

// ---------------------------------------------------------------------------
extern "C" void kernel_launch(void* const* d_in, const int* in_sizes, int n_in,
                              void* d_out, int out_size, void* d_ws, size_t ws_size,
                              hipStream_t stream) {
  const float* x     = (const float*)d_in[0];
  const float* wih1f = (const float*)d_in[1];
  const float* whh1f = (const float*)d_in[2];
  const float* bih1f = (const float*)d_in[3];
  const float* bhh1f = (const float*)d_in[4];
  const float* wih1b = (const float*)d_in[5];
  const float* whh1b = (const float*)d_in[6];
  const float* bih1b = (const float*)d_in[7];
  const float* bhh1b = (const float*)d_in[8];
  const float* wih2f = (const float*)d_in[9];
  const float* whh2f = (const float*)d_in[10];
  const float* bih2f = (const float*)d_in[11];
  const float* bhh2f = (const float*)d_in[12];
  const float* wih2b = (const float*)d_in[13];
  const float* whh2b = (const float*)d_in[14];
  const float* bih2b = (const float*)d_in[15];
  const float* bhh2b = (const float*)d_in[16];
  const float* fc1w  = (const float*)d_in[17];
  const float* fc1b  = (const float*)d_in[18];
  const float* fc2w  = (const float*)d_in[19];
  const float* fc2b  = (const float*)d_in[20];
  float* out = (float*)d_out;

  // workspace (169,287,680 B):
  //   region A: h2out (83.9 MB, linear)   region B: h1out (83.9 MB, tiled)
  //   + wswz1 / wswz2 / wfc / biasc
  if (ws_size < (size_t)169287680) return;
  _Float16* h2out = (_Float16*)d_ws;            // [16384][10][256] f16
  _Float16* h1out = h2out + (size_t)41943040;   // [1024][10][8][512] f16 tiled
  _Float16* wswz1 = h1out + (size_t)41943040;
  _Float16* wswz2 = wswz1 + 327680;
  _Float16* wfc   = wswz2 + 393216;
  float* biasc    = (float*)(wfc + 32768);

  prep_kernel<<<2952, 256, 0, stream>>>(
      wih1f, whh1f, bih1f, bhh1f, wih1b, whh1b, bih1b, bhh1b,
      wih2f, whh2f, bih2f, bhh2f, wih2b, whh2b, bih2b, bhh2b, fc1w,
      wswz1, wswz2, wfc, biasc);
  lstm_kernel<1><<<dim3(128, 2), 512, 0, stream>>>(x, wswz1, biasc, h1out);
  lstm_kernel<2><<<dim3(128, 2), 512, 0, stream>>>(h1out, wswz2, biasc + 1024, h2out);
  fc_kernel<<<256, 256, 0, stream>>>(h2out, wfc, fc1b, fc2w, fc2b, out);
}

// Round 5
// 554.812 us; speedup vs baseline: 1.5253x; 1.5253x over previous
//
#include <hip/hip_runtime.h>

typedef _Float16 half8_t __attribute__((ext_vector_type(8)));
typedef _Float16 half4_t __attribute__((ext_vector_type(4)));
typedef _Float16 half2_t __attribute__((ext_vector_type(2)));
typedef float floatx4 __attribute__((ext_vector_type(4)));
typedef float float4_t __attribute__((ext_vector_type(4)));
typedef unsigned int uint4_t __attribute__((ext_vector_type(4)));

__device__ __forceinline__ float sigm_f(float v) {
  return __builtin_amdgcn_rcpf(1.f + __expf(-v));
}
__device__ __forceinline__ float tanh_f(float v) {
  return 2.f * __builtin_amdgcn_rcpf(1.f + __expf(-2.f * v)) - 1.f;
}

__device__ __forceinline__ void gl_lds16(const _Float16* g, _Float16* l) {
  __builtin_amdgcn_global_load_lds(
      (const __attribute__((address_space(1))) void*)g,
      (__attribute__((address_space(3))) void*)l, 16, 0, 0);
}

// ---------------------------------------------------------------------------
// Weight prep: MFMA B-frag order, f16.  col n -> gate=(n>>4)&3,
// hcol=(n>>6)*16+(n&15); oc = gate*128+hcol.  L1 K rows: [0,184)=w_ih,
// [184,192)=0, [192,320)=w_hh.  L2: [0,256)=w_ih, [256,384)=w_hh.
// wswz[dir][kt][ntg=cs*4+nt][lane][8].
// ---------------------------------------------------------------------------
__global__ void prep_kernel(
    const float* __restrict__ wih1f, const float* __restrict__ whh1f,
    const float* __restrict__ bih1f, const float* __restrict__ bhh1f,
    const float* __restrict__ wih1b, const float* __restrict__ whh1b,
    const float* __restrict__ bih1b, const float* __restrict__ bhh1b,
    const float* __restrict__ wih2f, const float* __restrict__ whh2f,
    const float* __restrict__ bih2f, const float* __restrict__ bhh2f,
    const float* __restrict__ wih2b, const float* __restrict__ whh2b,
    const float* __restrict__ bih2b, const float* __restrict__ bhh2b,
    const float* __restrict__ fc1w,
    _Float16* __restrict__ wswz1, _Float16* __restrict__ wswz2,
    _Float16* __restrict__ wfc, float* __restrict__ biasc) {
  const int N1 = 327680, N2 = 393216, NF = 32768, NB = 2048;
  int idx = blockIdx.x * 256 + threadIdx.x;
  if (idx < N1) {
    int d = idx / 163840;
    int r = idx - d * 163840;
    int j = r & 7, lane = (r >> 3) & 63, ntg = (r >> 9) & 31, kt = r >> 14;
    int k = kt * 32 + (lane >> 4) * 8 + j;
    int n = ntg * 16 + (lane & 15);
    int oc = ((n >> 4) & 3) * 128 + (n >> 6) * 16 + (n & 15);
    const float* wih = d ? wih1b : wih1f;
    const float* whh = d ? whh1b : whh1f;
    float v = (k < 184) ? wih[oc * 184 + k]
                        : ((k < 192) ? 0.f : whh[oc * 128 + (k - 192)]);
    wswz1[idx] = (_Float16)v;
  } else if (idx < N1 + N2) {
    int r0 = idx - N1;
    int d = r0 / 196608;
    int r = r0 - d * 196608;
    int j = r & 7, lane = (r >> 3) & 63, ntg = (r >> 9) & 31, kt = r >> 14;
    int k = kt * 32 + (lane >> 4) * 8 + j;
    int n = ntg * 16 + (lane & 15);
    int oc = ((n >> 4) & 3) * 128 + (n >> 6) * 16 + (n & 15);
    const float* wih = d ? wih2b : wih2f;
    const float* whh = d ? whh2b : whh2f;
    float v = (k < 256) ? wih[oc * 256 + k] : whh[oc * 128 + (k - 256)];
    wswz2[r0] = (_Float16)v;
  } else if (idx < N1 + N2 + NF) {
    int r = idx - (N1 + N2);
    int j = r & 7, lane = (r >> 3) & 63, ntg = (r >> 9) & 3, kt = r >> 11;
    int k = kt * 32 + (lane >> 4) * 8 + j;
    int n = ntg * 16 + (lane & 15);
    wfc[r] = (_Float16)fc1w[n * 512 + k];
  } else if (idx < N1 + N2 + NF + NB) {
    int r = idx - (N1 + N2 + NF);
    int n = r & 511, d = (r >> 9) & 1, l = r >> 10;
    int oc = ((n >> 4) & 3) * 128 + (n >> 6) * 16 + (n & 15);
    const float* bi = l ? (d ? bih2b : bih2f) : (d ? bih1b : bih1f);
    const float* bh = l ? (d ? bhh2b : bhh2f) : (d ? bhh1b : bhh1f);
    biasc[r] = bi[oc] + bh[oc];
  }
}

// ---------------------------------------------------------------------------
// LSTM v5 — weight-stationary.  512 thr = 8 waves (one per 64-col strip),
// M=32 rows/block (mt=2).  Each wave holds kts [0,RKT) of its strip in
// REGISTERS (loaded once); kts [RKT,KT) live in a one-time LDS copy.
// Zero in-loop weight traffic.  Double-buffered Xbuf, 2 barriers/t.
// LAYER2 fuses the temporal maxpool (running max in regs) and writes only
// the pooled [B][512] tensor (h2 sequence never materialized).
// ---------------------------------------------------------------------------
template <int LAYER>
__global__ __launch_bounds__(512, 2) void lstm_kernel(
    const void* __restrict__ xin_v, const _Float16* __restrict__ wswz,
    const float* __restrict__ biasc, _Float16* __restrict__ outp) {
  constexpr int XT = (LAYER == 1) ? 6 : 8;   // x k-tiles
  constexpr int KT = XT + 4;                 // 10 / 12
  constexpr int RKT = (LAYER == 1) ? 8 : 9;  // register-resident kts
  constexpr int LKT = KT - RKT;              // LDS-resident kts: 2 / 3
  constexpr int XHALF = XT * 1024;           // halfs per X buffer

  __shared__ __align__(16) _Float16 Xbuf[2 * XHALF];   // 24 / 32 KB
  __shared__ __align__(16) _Float16 Hbuf[4096];        // 8 KB
  __shared__ __align__(16) _Float16 Wlds[LKT * 16384]; // 64 / 96 KB

  const int tid = threadIdx.x;
  const int cs = tid >> 6;
  const int lane = tid & 63;
  const int q = lane >> 4;
  const int l15 = lane & 15;
  const int lane8 = lane * 8;
  const int dir = blockIdx.y;
  const int row0 = blockIdx.x << 5;  // 32 rows/block
  const int rt0 = blockIdx.x << 1;   // 2 rowtiles

  const _Float16* __restrict__ wd = wswz + (size_t)dir * (KT * 16384);
  const float* __restrict__ bd = biasc + (dir << 9);

  float bias_frag[4];
#pragma unroll
  for (int nt = 0; nt < 4; ++nt) bias_frag[nt] = bd[(cs << 6) + (nt << 4) + l15];

  // ---- weights: registers (once) + LDS remainder (once)
  half8_t Wreg[RKT][4];
#pragma unroll
  for (int i = 0; i < RKT; ++i) {
    const _Float16* p = wd + (((size_t)i * 32 + (cs << 2)) * 64 + lane) * 8;
#pragma unroll
    for (int nt = 0; nt < 4; ++nt) Wreg[i][nt] = *(const half8_t*)(p + nt * 512);
  }
#pragma unroll
  for (int it = 0; it < LKT * 4; ++it) {
    int u = tid + it * 512;
    gl_lds16(wd + (size_t)RKT * 16384 + u * 8, Wlds + u * 8);
  }

  // ---- staging helpers
  float4_t xs[3];
  auto l1_load = [&](int te) {
#pragma unroll
    for (int it = 0; it < 3; ++it) {
      int u = tid + it * 512;
      if (u < 1472) {
        int r = u / 46, c = u - r * 46;
        xs[it] = __builtin_nontemporal_load(
            (const float4_t*)((const float*)xin_v + (size_t)(row0 + r) * 1840 +
                              te * 184 + (c << 2)));
      }
    }
  };
  auto l1_write = [&](int buf) {
    _Float16* xb = Xbuf + buf * XHALF;
#pragma unroll
    for (int it = 0; it < 3; ++it) {
      int u = tid + it * 512;
      if (u < 1472) {
        int r = u / 46, c = u - r * 46, k0 = c << 2;
        half4_t hv;
        hv[0] = (_Float16)xs[it][0]; hv[1] = (_Float16)xs[it][1];
        hv[2] = (_Float16)xs[it][2]; hv[3] = (_Float16)xs[it][3];
        *(half4_t*)(xb + ((k0 >> 5) * 2 + (r >> 4)) * 512 +
                    ((k0 & 31) >> 3) * 128 + (r & 15) * 8 + (k0 & 7)) = hv;
      }
    }
  };
  auto l2_stage = [&](int buf, int te) {
    const _Float16* xf = (const _Float16*)xin_v;
    _Float16* xb = Xbuf + buf * XHALF;
#pragma unroll
    for (int it = 0; it < 2; ++it) {
      int u = tid + it * 512;
      int kt = u >> 7, mt = (u >> 6) & 1, v = u & 63;
      gl_lds16(xf + ((size_t)((rt0 + mt) * 10 + te) * 8 + kt) * 512 + v * 8,
               xb + u * 8);
    }
  };

  // zero Hbuf (h0 = 0)
  {
    uint4_t z = {0u, 0u, 0u, 0u};
    *(uint4_t*)(Hbuf + tid * 8) = z;
    // L1: zero the pad region (k 184..191) of both X buffers, once
    if (LAYER == 1 && tid < 64) {
      half8_t hz;
#pragma unroll
      for (int j = 0; j < 8; ++j) hz[j] = (_Float16)0.f;
      int buf = tid >> 5, r = tid & 31;
      *(half8_t*)(Xbuf + buf * XHALF + (10 + (r >> 4)) * 512 + 384 + (r & 15) * 8) = hz;
    }
  }

  // initial stage (t=0)
  const int te0 = dir ? 9 : 0;
  if (LAYER == 1) { l1_load(te0); l1_write(0); } else { l2_stage(0, te0); }

  float c_state[2][4];
#pragma unroll
  for (int mt = 0; mt < 2; ++mt)
#pragma unroll
    for (int rg = 0; rg < 4; ++rg) c_state[mt][rg] = 0.f;

  float gmax[2][2][4];
  if (LAYER == 2) {
#pragma unroll
    for (int g = 0; g < 2; ++g)
#pragma unroll
      for (int mt = 0; mt < 2; ++mt)
#pragma unroll
        for (int rg = 0; rg < 4; ++rg) gmax[g][mt][rg] = -1e30f;
  }

  __syncthreads();  // weights-LDS + Xbuf(0) + Hbuf zero all visible

  for (int t = 0; t < 10; ++t) {
    const int te = dir ? (9 - t) : t;
    const int cur = t & 1;

    // issue next-t staging (into alt buffer; its readers finished last barrier)
    if (t < 9) {
      const int ten = dir ? (8 - t) : (t + 1);
      if (LAYER == 1) l1_load(ten);
      else l2_stage(cur ^ 1, ten);
    }

    floatx4 acc[2][4];
#pragma unroll
    for (int mt = 0; mt < 2; ++mt)
#pragma unroll
      for (int nt = 0; nt < 4; ++nt) {
        floatx4 b4 = {bias_frag[nt], bias_frag[nt], bias_frag[nt], bias_frag[nt]};
        acc[mt][nt] = b4;
      }

    // ---- GEMM over all kts; weights from regs/LDS only
    const _Float16* xc = Xbuf + cur * XHALF;
#pragma unroll
    for (int i = 0; i < KT; ++i) {
      half8_t bl[4];
      if (i < RKT) {
#pragma unroll
        for (int nt = 0; nt < 4; ++nt) bl[nt] = Wreg[i][nt];
      } else {
#pragma unroll
        for (int nt = 0; nt < 4; ++nt)
          bl[nt] = *(const half8_t*)(Wlds + (i - RKT) * 16384 +
                                     (((cs << 2) + nt) * 64 + lane) * 8);
      }
      const _Float16* abase =
          (i < XT) ? (xc + i * 1024 + lane8) : (Hbuf + (i - XT) * 1024 + lane8);
#pragma unroll
      for (int mt = 0; mt < 2; ++mt) {
        half8_t a = *(const half8_t*)(abase + mt * 512);
#pragma unroll
        for (int nt = 0; nt < 4; ++nt)
          acc[mt][nt] = __builtin_amdgcn_mfma_f32_16x16x32_f16(a, bl[nt], acc[mt][nt], 0, 0, 0);
      }
    }

    // ---- layer1: write back h(t-1) (Hbuf still stable), tiled layout
    if (LAYER == 1 && t > 0) {
      const int t_prev = dir ? (10 - t) : (t - 1);
      int u = tid, hk = u >> 7, mt = (u >> 6) & 1, v = u & 63;
      __builtin_nontemporal_store(
          *(const uint4_t*)(Hbuf + u * 8),
          (uint4_t*)(outp + (((size_t)(rt0 + mt) * 10 + t_prev) * 8 + (dir << 2) + hk) * 512 +
                     v * 8));
    }
    // ---- layer1: commit staged x into alt buffer (no readers there)
    if (LAYER == 1 && t < 9) l1_write(cur ^ 1);

    __syncthreads();  // all Hbuf/Xbuf(cur) reads done

    // ---- LSTM cell (nt == gate); h(t) -> Hbuf (A-frag order)
#pragma unroll
    for (int mt = 0; mt < 2; ++mt) {
#pragma unroll
      for (int rg = 0; rg < 4; ++rg) {
        float ig = sigm_f(acc[mt][0][rg]);
        float fg = sigm_f(acc[mt][1][rg]);
        float gg = tanh_f(acc[mt][2][rg]);
        float og = sigm_f(acc[mt][3][rg]);
        float c = fg * c_state[mt][rg] + ig * gg;
        c_state[mt][rg] = c;
        float h = og * tanh_f(c);
        if (LAYER == 2) {
          int g = (te < 5) ? 0 : 1;
          gmax[g][mt][rg] = fmaxf(gmax[g][mt][rg], h);
        }
        Hbuf[((cs >> 1) * 2 + mt) * 512 + (((cs & 1) * 2) + (l15 >> 3)) * 128 +
             ((q << 2) + rg) * 8 + (l15 & 7)] = (_Float16)h;
      }
    }
    __syncthreads();  // h(t) visible; alt-buffer staging arrived (barrier drains)
  }

  if (LAYER == 1) {
    // final writeback h(t=9)
    const int t_last = dir ? 0 : 9;
    int u = tid, hk = u >> 7, mt = (u >> 6) & 1, v = u & 63;
    __builtin_nontemporal_store(
        *(const uint4_t*)(Hbuf + u * 8),
        (uint4_t*)(outp + (((size_t)(rt0 + mt) * 10 + t_last) * 8 + (dir << 2) + hk) * 512 +
                   v * 8));
  } else {
    // pooled output: P[r][hcol*2+g], then coalesced copy (dir half of 512)
    _Float16* P = Xbuf;  // 32*256 halfs, free after last barrier
#pragma unroll
    for (int mt = 0; mt < 2; ++mt)
#pragma unroll
      for (int rg = 0; rg < 4; ++rg)
#pragma unroll
        for (int g = 0; g < 2; ++g)
          P[(mt * 16 + (q << 2) + rg) * 256 + ((cs << 4) + l15) * 2 + g] =
              (_Float16)gmax[g][mt][rg];
    __syncthreads();
#pragma unroll
    for (int it = 0; it < 2; ++it) {
      int u = tid + it * 512;
      int r = u >> 5, v = u & 31;
      __builtin_nontemporal_store(
          *(const uint4_t*)(P + u * 8),
          (uint4_t*)(outp + (size_t)(row0 + r) * 512 + (dir << 8) + v * 8));
    }
  }
}

// ---------------------------------------------------------------------------
// FC head: pooled [B][512] f16 -> fc1(relu) -> fc2.  Maxpool already fused
// into lstm2.  64 samples/block, 256 thr.
// ---------------------------------------------------------------------------
__global__ __launch_bounds__(256) void fc_kernel(
    const _Float16* __restrict__ pooled_g, const _Float16* __restrict__ wfc,
    const float* __restrict__ fc1b, const float* __restrict__ fc2w,
    const float* __restrict__ fc2b, float* __restrict__ out) {
  __shared__ __align__(16) _Float16 pooled[64 * 520];
  const int tid = threadIdx.x;
  const int s0 = blockIdx.x << 6;

#pragma unroll
  for (int it = 0; it < 16; ++it) {
    int u = tid + it * 256;
    int s = u >> 6, v = u & 63;
    *(uint4_t*)(pooled + s * 520 + v * 8) =
        *(const uint4_t*)(pooled_g + (size_t)(s0 + s) * 512 + v * 8);
  }
  __syncthreads();

  const int wid = tid >> 6, lane = tid & 63, q = lane >> 4, l15 = lane & 15;
  const int m0 = wid << 4;

  const floatx4 fzero = {0.f, 0.f, 0.f, 0.f};
  floatx4 acc[4];
#pragma unroll
  for (int nt = 0; nt < 4; ++nt) acc[nt] = fzero;

#pragma unroll
  for (int kt = 0; kt < 16; ++kt) {
    half8_t a = *(const half8_t*)(pooled + (m0 + l15) * 520 + (kt << 5) + (q << 3));
#pragma unroll
    for (int nt = 0; nt < 4; ++nt) {
      half8_t b = *(const half8_t*)(wfc + ((((size_t)kt << 2) + nt) * 64 + lane) * 8);
      acc[nt] = __builtin_amdgcn_mfma_f32_16x16x32_f16(a, b, acc[nt], 0, 0, 0);
    }
  }

  float b1[4], w2[4];
#pragma unroll
  for (int nt = 0; nt < 4; ++nt) {
    b1[nt] = fc1b[(nt << 4) + l15];
    w2[nt] = fc2w[(nt << 4) + l15];
  }
  const float c2b = fc2b[0];

#pragma unroll
  for (int rg = 0; rg < 4; ++rg) {
    float v = 0.f;
#pragma unroll
    for (int nt = 0; nt < 4; ++nt)
      v += fmaxf(acc[nt][rg] + b1[nt], 0.f) * w2[nt];
    v += __shfl_xor(v, 1, 64);
    v += __shfl_xor(v, 2, 64);
    v += __shfl_xor(v, 4, 64);
    v += __shfl_xor(v, 8, 64);
    if (l15 == 0) out[s0 + m0 + (q << 2) + rg] = v + c2b;
  }
}

// ---------------------------------------------------------------------------
extern "C" void kernel_launch(void* const* d_in, const int* in_sizes, int n_in,
                              void* d_out, int out_size, void* d_ws, size_t ws_size,
                              hipStream_t stream) {
  const float* x     = (const float*)d_in[0];
  const float* wih1f = (const float*)d_in[1];
  const float* whh1f = (const float*)d_in[2];
  const float* bih1f = (const float*)d_in[3];
  const float* bhh1f = (const float*)d_in[4];
  const float* wih1b = (const float*)d_in[5];
  const float* whh1b = (const float*)d_in[6];
  const float* bih1b = (const float*)d_in[7];
  const float* bhh1b = (const float*)d_in[8];
  const float* wih2f = (const float*)d_in[9];
  const float* whh2f = (const float*)d_in[10];
  const float* bih2f = (const float*)d_in[11];
  const float* bhh2f = (const float*)d_in[12];
  const float* wih2b = (const float*)d_in[13];
  const float* whh2b = (const float*)d_in[14];
  const float* bih2b = (const float*)d_in[15];
  const float* bhh2b = (const float*)d_in[16];
  const float* fc1w  = (const float*)d_in[17];
  const float* fc1b  = (const float*)d_in[18];
  const float* fc2w  = (const float*)d_in[19];
  const float* fc2b  = (const float*)d_in[20];
  float* out = (float*)d_out;

  // workspace (halfs): pooled_g 8,388,608 | h1out 41,943,040 (tiled) |
  //                    wswz1 327,680 | wswz2 393,216 | wfc 32,768 | biasc f32
  if (ws_size < (size_t)169287680) return;
  _Float16* pooled_g = (_Float16*)d_ws;          // [16384][512]
  _Float16* h1out = pooled_g + (size_t)8388608;  // [1024 rt][10][8][512]
  _Float16* wswz1 = h1out + (size_t)41943040;
  _Float16* wswz2 = wswz1 + 327680;
  _Float16* wfc   = wswz2 + 393216;
  float* biasc    = (float*)(wfc + 32768);

  prep_kernel<<<2952, 256, 0, stream>>>(
      wih1f, whh1f, bih1f, bhh1f, wih1b, whh1b, bih1b, bhh1b,
      wih2f, whh2f, bih2f, bhh2f, wih2b, whh2b, bih2b, bhh2b, fc1w,
      wswz1, wswz2, wfc, biasc);
  lstm_kernel<1><<<dim3(512, 2), 512, 0, stream>>>(x, wswz1, biasc, h1out);
  lstm_kernel<2><<<dim3(512, 2), 512, 0, stream>>>(h1out, wswz2, biasc + 1024, pooled_g);
  fc_kernel<<<256, 256, 0, stream>>>(pooled_g, wfc, fc1b, fc2w, fc2b, out);
}

// Round 6
// 508.579 us; speedup vs baseline: 1.6640x; 1.0909x over previous
//
#include <hip/hip_runtime.h>

typedef _Float16 half8_t __attribute__((ext_vector_type(8)));
typedef _Float16 half4_t __attribute__((ext_vector_type(4)));
typedef _Float16 half2_t __attribute__((ext_vector_type(2)));
typedef float floatx4 __attribute__((ext_vector_type(4)));
typedef float float4_t __attribute__((ext_vector_type(4)));
typedef unsigned int uint4_t __attribute__((ext_vector_type(4)));

__device__ __forceinline__ float sigm_f(float v) {
  return __builtin_amdgcn_rcpf(1.f + __expf(-v));
}
__device__ __forceinline__ float tanh_f(float v) {
  return 2.f * __builtin_amdgcn_rcpf(1.f + __expf(-2.f * v)) - 1.f;
}

__device__ __forceinline__ void gl_lds16(const _Float16* g, _Float16* l) {
  __builtin_amdgcn_global_load_lds(
      (const __attribute__((address_space(1))) void*)g,
      (__attribute__((address_space(3))) void*)l, 16, 0, 0);
}

// ---------------------------------------------------------------------------
// Weight prep: MFMA B-frag order, f16.  col n -> gate=(n>>4)&3,
// hcol=(n>>6)*16+(n&15); oc = gate*128+hcol.  L1 K rows: [0,184)=w_ih,
// [184,192)=0, [192,320)=w_hh.  L2: [0,256)=w_ih, [256,384)=w_hh.
// ---------------------------------------------------------------------------
__global__ void prep_kernel(
    const float* __restrict__ wih1f, const float* __restrict__ whh1f,
    const float* __restrict__ bih1f, const float* __restrict__ bhh1f,
    const float* __restrict__ wih1b, const float* __restrict__ whh1b,
    const float* __restrict__ bih1b, const float* __restrict__ bhh1b,
    const float* __restrict__ wih2f, const float* __restrict__ whh2f,
    const float* __restrict__ bih2f, const float* __restrict__ bhh2f,
    const float* __restrict__ wih2b, const float* __restrict__ whh2b,
    const float* __restrict__ bih2b, const float* __restrict__ bhh2b,
    const float* __restrict__ fc1w,
    _Float16* __restrict__ wswz1, _Float16* __restrict__ wswz2,
    _Float16* __restrict__ wfc, float* __restrict__ biasc) {
  const int N1 = 327680, N2 = 393216, NF = 32768, NB = 2048;
  int idx = blockIdx.x * 256 + threadIdx.x;
  if (idx < N1) {
    int d = idx / 163840;
    int r = idx - d * 163840;
    int j = r & 7, lane = (r >> 3) & 63, ntg = (r >> 9) & 31, kt = r >> 14;
    int k = kt * 32 + (lane >> 4) * 8 + j;
    int n = ntg * 16 + (lane & 15);
    int oc = ((n >> 4) & 3) * 128 + (n >> 6) * 16 + (n & 15);
    const float* wih = d ? wih1b : wih1f;
    const float* whh = d ? whh1b : whh1f;
    float v = (k < 184) ? wih[oc * 184 + k]
                        : ((k < 192) ? 0.f : whh[oc * 128 + (k - 192)]);
    wswz1[idx] = (_Float16)v;
  } else if (idx < N1 + N2) {
    int r0 = idx - N1;
    int d = r0 / 196608;
    int r = r0 - d * 196608;
    int j = r & 7, lane = (r >> 3) & 63, ntg = (r >> 9) & 31, kt = r >> 14;
    int k = kt * 32 + (lane >> 4) * 8 + j;
    int n = ntg * 16 + (lane & 15);
    int oc = ((n >> 4) & 3) * 128 + (n >> 6) * 16 + (n & 15);
    const float* wih = d ? wih2b : wih2f;
    const float* whh = d ? whh2b : whh2f;
    float v = (k < 256) ? wih[oc * 256 + k] : whh[oc * 128 + (k - 256)];
    wswz2[r0] = (_Float16)v;
  } else if (idx < N1 + N2 + NF) {
    int r = idx - (N1 + N2);
    int j = r & 7, lane = (r >> 3) & 63, ntg = (r >> 9) & 3, kt = r >> 11;
    int k = kt * 32 + (lane >> 4) * 8 + j;
    int n = ntg * 16 + (lane & 15);
    wfc[r] = (_Float16)fc1w[n * 512 + k];
  } else if (idx < N1 + N2 + NF + NB) {
    int r = idx - (N1 + N2 + NF);
    int n = r & 511, d = (r >> 9) & 1, l = r >> 10;
    int oc = ((n >> 4) & 3) * 128 + (n >> 6) * 16 + (n & 15);
    const float* bi = l ? (d ? bih2b : bih2f) : (d ? bih1b : bih1f);
    const float* bh = l ? (d ? bhh2b : bhh2f) : (d ? bhh1b : bhh1f);
    biasc[r] = bi[oc] + bh[oc];
  }
}

// ---------------------------------------------------------------------------
// LSTM v6 — weight-stationary + 1-barrier/t software pipeline.
// 512 thr = 8 waves (one per 64-col strip), M=32 rows/block.
// Weights: kts [0,RKT) in registers, [RKT,KT) in one-time LDS copy.
// Per t: [stage(t+2)] wb(t-1,L1) R-GEMM(t) cell(t) [l1_write(t+2)]
//        X-GEMM(t+1) barrier.  Hbuf double-buffered (WAR barrier removed);
// X-phase of t+1 is h(t)-independent and overlaps the cell/barrier tail.
// LAYER2 fuses temporal maxpool; writes only pooled [B][512].
// ---------------------------------------------------------------------------
template <int LAYER>
__global__ __launch_bounds__(512, 2) void lstm_kernel(
    const void* __restrict__ xin_v, const _Float16* __restrict__ wswz,
    const float* __restrict__ biasc, _Float16* __restrict__ outp) {
  constexpr int XT = (LAYER == 1) ? 6 : 8;   // x k-tiles
  constexpr int KT = XT + 4;                 // 10 / 12
  constexpr int RKT = (LAYER == 1) ? 8 : 9;  // register-resident kts
  constexpr int LKT = KT - RKT;              // LDS-resident kts: 2 / 3
  constexpr int XHALF = XT * 1024;           // halfs per X buffer

  __shared__ __align__(16) _Float16 Xbuf[2 * XHALF];   // 24 / 32 KB
  __shared__ __align__(16) _Float16 Hbuf[2 * 4096];    // 16 KB (double-buf)
  __shared__ __align__(16) _Float16 Wlds[LKT * 16384]; // 64 / 96 KB

  const int tid = threadIdx.x;
  const int cs = tid >> 6;
  const int lane = tid & 63;
  const int q = lane >> 4;
  const int l15 = lane & 15;
  const int lane8 = lane * 8;
  const int dir = blockIdx.y;
  const int row0 = blockIdx.x << 5;  // 32 rows/block
  const int rt0 = blockIdx.x << 1;   // 2 rowtiles

  const _Float16* __restrict__ wd = wswz + (size_t)dir * (KT * 16384);
  const float* __restrict__ bd = biasc + (dir << 9);

  float bias_frag[4];
#pragma unroll
  for (int nt = 0; nt < 4; ++nt) bias_frag[nt] = bd[(cs << 6) + (nt << 4) + l15];

  // ---- weights: registers (once) + LDS remainder (once)
  half8_t Wreg[RKT][4];
#pragma unroll
  for (int i = 0; i < RKT; ++i) {
    const _Float16* p = wd + (((size_t)i * 32 + (cs << 2)) * 64 + lane) * 8;
#pragma unroll
    for (int nt = 0; nt < 4; ++nt) Wreg[i][nt] = *(const half8_t*)(p + nt * 512);
  }
#pragma unroll
  for (int it = 0; it < LKT * 4; ++it) {
    int u = tid + it * 512;
    gl_lds16(wd + (size_t)RKT * 16384 + u * 8, Wlds + u * 8);
  }

  // ---- staging helpers
  float4_t xs[3];
  auto l1_load = [&](int te) {
#pragma unroll
    for (int it = 0; it < 3; ++it) {
      int u = tid + it * 512;
      if (u < 1472) {
        int r = u / 46, c = u - r * 46;
        xs[it] = __builtin_nontemporal_load(
            (const float4_t*)((const float*)xin_v + (size_t)(row0 + r) * 1840 +
                              te * 184 + (c << 2)));
      }
    }
  };
  auto l1_write = [&](int buf) {
    _Float16* xb = Xbuf + buf * XHALF;
#pragma unroll
    for (int it = 0; it < 3; ++it) {
      int u = tid + it * 512;
      if (u < 1472) {
        int r = u / 46, c = u - r * 46, k0 = c << 2;
        half4_t hv;
        hv[0] = (_Float16)xs[it][0]; hv[1] = (_Float16)xs[it][1];
        hv[2] = (_Float16)xs[it][2]; hv[3] = (_Float16)xs[it][3];
        *(half4_t*)(xb + ((k0 >> 5) * 2 + (r >> 4)) * 512 +
                    ((k0 & 31) >> 3) * 128 + (r & 15) * 8 + (k0 & 7)) = hv;
      }
    }
  };
  auto l2_stage = [&](int buf, int te) {
    const _Float16* xf = (const _Float16*)xin_v;
    _Float16* xb = Xbuf + buf * XHALF;
#pragma unroll
    for (int it = 0; it < 2; ++it) {
      int u = tid + it * 512;
      int kt = u >> 7, mt = (u >> 6) & 1, v = u & 63;
      gl_lds16(xf + ((size_t)((rt0 + mt) * 10 + te) * 8 + kt) * 512 + v * 8,
               xb + u * 8);
    }
  };

  // B-fragment fetch (kt compile-time in unrolled loops)
  auto bfrag = [&](int kt, half8_t* bl) {
    if (kt < RKT) {
#pragma unroll
      for (int nt = 0; nt < 4; ++nt) bl[nt] = Wreg[kt][nt];
    } else {
#pragma unroll
      for (int nt = 0; nt < 4; ++nt)
        bl[nt] = *(const half8_t*)(Wlds + (kt - RKT) * 16384 +
                                   (((cs << 2) + nt) * 64 + lane) * 8);
    }
  };
  auto xgemm = [&](const _Float16* xb, floatx4 (*ac)[4]) {
#pragma unroll
    for (int i = 0; i < XT; ++i) {
      half8_t bl[4];
      bfrag(i, bl);
#pragma unroll
      for (int mt = 0; mt < 2; ++mt) {
        half8_t a = *(const half8_t*)(xb + i * 1024 + mt * 512 + lane8);
#pragma unroll
        for (int nt = 0; nt < 4; ++nt)
          ac[mt][nt] = __builtin_amdgcn_mfma_f32_16x16x32_f16(a, bl[nt], ac[mt][nt], 0, 0, 0);
      }
    }
  };
  auto accinit = [&](floatx4 (*ac)[4]) {
#pragma unroll
    for (int mt = 0; mt < 2; ++mt)
#pragma unroll
      for (int nt = 0; nt < 4; ++nt) {
        floatx4 b4 = {bias_frag[nt], bias_frag[nt], bias_frag[nt], bias_frag[nt]};
        ac[mt][nt] = b4;
      }
  };

  // zero Hbuf[0] (h(-1)=0); L1: zero pad cols of both X buffers once
  {
    uint4_t z = {0u, 0u, 0u, 0u};
    *(uint4_t*)(Hbuf + tid * 8) = z;
    if (LAYER == 1 && tid < 64) {
      half8_t hz;
#pragma unroll
      for (int j = 0; j < 8; ++j) hz[j] = (_Float16)0.f;
      int buf = tid >> 5, r = tid & 31;
      *(half8_t*)(Xbuf + buf * XHALF + (10 + (r >> 4)) * 512 + 384 + (r & 15) * 8) = hz;
    }
  }

  // preloop: stage t=0 and t=1
  const int te0 = dir ? 9 : 0;
  const int te1 = dir ? 8 : 1;
  if (LAYER == 1) {
    l1_load(te0); l1_write(0);
    l1_load(te1); l1_write(1);
  } else {
    l2_stage(0, te0);
    l2_stage(1, te1);
  }

  float c_state[2][4];
#pragma unroll
  for (int mt = 0; mt < 2; ++mt)
#pragma unroll
    for (int rg = 0; rg < 4; ++rg) c_state[mt][rg] = 0.f;

  float gmax[2][2][4];
  if (LAYER == 2) {
#pragma unroll
    for (int g = 0; g < 2; ++g)
#pragma unroll
      for (int mt = 0; mt < 2; ++mt)
#pragma unroll
        for (int rg = 0; rg < 4; ++rg) gmax[g][mt][rg] = -1e30f;
  }

  __syncthreads();  // weights-LDS + Xbuf(0/1) + Hbuf zero visible

  floatx4 acc[2][4];
  accinit(acc);
  xgemm(Xbuf, acc);  // X(0)
  __syncthreads();   // protect buf0 from iter0's stage(2)

  for (int t = 0; t < 10; ++t) {
    const int cur = t & 1;
    const int te = dir ? (9 - t) : t;

    // stage t+2 into buf[cur] (readers finished before last barrier)
    if (t < 8) {
      const int te2 = dir ? (7 - t) : (t + 2);
      if (LAYER == 1) l1_load(te2);
      else l2_stage(cur, te2);
    }

    // L1: write back h(t-1) from Hbuf[cur] (stable this iter)
    if (LAYER == 1 && t > 0) {
      const int t_prev = dir ? (10 - t) : (t - 1);
      int u = tid, hk = u >> 7, mt = (u >> 6) & 1, v = u & 63;
      __builtin_nontemporal_store(
          *(const uint4_t*)(Hbuf + cur * 4096 + u * 8),
          (uint4_t*)(outp + (((size_t)(rt0 + mt) * 10 + t_prev) * 8 + (dir << 2) + hk) * 512 +
                     v * 8));
    }

    // ---- R(t): recurrent GEMM, A = h(t-1) from Hbuf[cur]
    const _Float16* hb = Hbuf + cur * 4096;
#pragma unroll
    for (int i = 0; i < 4; ++i) {
      half8_t bl[4];
      bfrag(XT + i, bl);
#pragma unroll
      for (int mt = 0; mt < 2; ++mt) {
        half8_t a = *(const half8_t*)(hb + i * 1024 + mt * 512 + lane8);
#pragma unroll
        for (int nt = 0; nt < 4; ++nt)
          acc[mt][nt] = __builtin_amdgcn_mfma_f32_16x16x32_f16(a, bl[nt], acc[mt][nt], 0, 0, 0);
      }
    }

    // ---- cell(t): h(t) -> Hbuf[cur^1] (A-frag order); L2: fused maxpool
    _Float16* hw = Hbuf + (cur ^ 1) * 4096;
#pragma unroll
    for (int mt = 0; mt < 2; ++mt) {
#pragma unroll
      for (int rg = 0; rg < 4; ++rg) {
        float ig = sigm_f(acc[mt][0][rg]);
        float fg = sigm_f(acc[mt][1][rg]);
        float gg = tanh_f(acc[mt][2][rg]);
        float og = sigm_f(acc[mt][3][rg]);
        float c = fg * c_state[mt][rg] + ig * gg;
        c_state[mt][rg] = c;
        float h = og * tanh_f(c);
        if (LAYER == 2) {
          int g = (te < 5) ? 0 : 1;
          gmax[g][mt][rg] = fmaxf(gmax[g][mt][rg], h);
        }
        hw[((cs >> 1) * 2 + mt) * 512 + (((cs & 1) * 2) + (l15 >> 3)) * 128 +
           ((q << 2) + rg) * 8 + (l15 & 7)] = (_Float16)h;
      }
    }

    // L1: commit staged x(t+2) into buf[cur]
    if (LAYER == 1 && t < 8) l1_write(cur);

    // ---- X(t+1): h-independent x-GEMM into fresh acc (overlaps barrier tail)
    if (t < 9) {
      floatx4 accN[2][4];
      accinit(accN);
      xgemm(Xbuf + (cur ^ 1) * XHALF, accN);
#pragma unroll
      for (int mt = 0; mt < 2; ++mt)
#pragma unroll
        for (int nt = 0; nt < 4; ++nt) acc[mt][nt] = accN[mt][nt];
    }

    __syncthreads();  // RAW on Hbuf[cur^1]; drains this iter's staging
  }

  if (LAYER == 1) {
    // final writeback h(t=9) (in Hbuf[0]: (9+1)&1)
    const int t_last = dir ? 0 : 9;
    int u = tid, hk = u >> 7, mt = (u >> 6) & 1, v = u & 63;
    __builtin_nontemporal_store(
        *(const uint4_t*)(Hbuf + u * 8),
        (uint4_t*)(outp + (((size_t)(rt0 + mt) * 10 + t_last) * 8 + (dir << 2) + hk) * 512 +
                   v * 8));
  } else {
    // pooled output: P[r][hcol*2+g], then coalesced copy (dir half of 512)
    _Float16* P = Xbuf;  // free after last barrier
#pragma unroll
    for (int mt = 0; mt < 2; ++mt)
#pragma unroll
      for (int rg = 0; rg < 4; ++rg)
#pragma unroll
        for (int g = 0; g < 2; ++g)
          P[(mt * 16 + (q << 2) + rg) * 256 + ((cs << 4) + l15) * 2 + g] =
              (_Float16)gmax[g][mt][rg];
    __syncthreads();
#pragma unroll
    for (int it = 0; it < 2; ++it) {
      int u = tid + it * 512;
      int r = u >> 5, v = u & 31;
      __builtin_nontemporal_store(
          *(const uint4_t*)(P + u * 8),
          (uint4_t*)(outp + (size_t)(row0 + r) * 512 + (dir << 8) + v * 8));
    }
  }
}

// ---------------------------------------------------------------------------
// FC head: pooled [B][512] f16 -> fc1(relu) -> fc2.  64 samples/block.
// ---------------------------------------------------------------------------
__global__ __launch_bounds__(256) void fc_kernel(
    const _Float16* __restrict__ pooled_g, const _Float16* __restrict__ wfc,
    const float* __restrict__ fc1b, const float* __restrict__ fc2w,
    const float* __restrict__ fc2b, float* __restrict__ out) {
  __shared__ __align__(16) _Float16 pooled[64 * 520];
  const int tid = threadIdx.x;
  const int s0 = blockIdx.x << 6;

#pragma unroll
  for (int it = 0; it < 16; ++it) {
    int u = tid + it * 256;
    int s = u >> 6, v = u & 63;
    *(uint4_t*)(pooled + s * 520 + v * 8) =
        *(const uint4_t*)(pooled_g + (size_t)(s0 + s) * 512 + v * 8);
  }
  __syncthreads();

  const int wid = tid >> 6, lane = tid & 63, q = lane >> 4, l15 = lane & 15;
  const int m0 = wid << 4;

  const floatx4 fzero = {0.f, 0.f, 0.f, 0.f};
  floatx4 acc[4];
#pragma unroll
  for (int nt = 0; nt < 4; ++nt) acc[nt] = fzero;

#pragma unroll
  for (int kt = 0; kt < 16; ++kt) {
    half8_t a = *(const half8_t*)(pooled + (m0 + l15) * 520 + (kt << 5) + (q << 3));
#pragma unroll
    for (int nt = 0; nt < 4; ++nt) {
      half8_t b = *(const half8_t*)(wfc + ((((size_t)kt << 2) + nt) * 64 + lane) * 8);
      acc[nt] = __builtin_amdgcn_mfma_f32_16x16x32_f16(a, b, acc[nt], 0, 0, 0);
    }
  }

  float b1[4], w2[4];
#pragma unroll
  for (int nt = 0; nt < 4; ++nt) {
    b1[nt] = fc1b[(nt << 4) + l15];
    w2[nt] = fc2w[(nt << 4) + l15];
  }
  const float c2b = fc2b[0];

#pragma unroll
  for (int rg = 0; rg < 4; ++rg) {
    float v = 0.f;
#pragma unroll
    for (int nt = 0; nt < 4; ++nt)
      v += fmaxf(acc[nt][rg] + b1[nt], 0.f) * w2[nt];
    v += __shfl_xor(v, 1, 64);
    v += __shfl_xor(v, 2, 64);
    v += __shfl_xor(v, 4, 64);
    v += __shfl_xor(v, 8, 64);
    if (l15 == 0) out[s0 + m0 + (q << 2) + rg] = v + c2b;
  }
}

// ---------------------------------------------------------------------------
extern "C" void kernel_launch(void* const* d_in, const int* in_sizes, int n_in,
                              void* d_out, int out_size, void* d_ws, size_t ws_size,
                              hipStream_t stream) {
  const float* x     = (const float*)d_in[0];
  const float* wih1f = (const float*)d_in[1];
  const float* whh1f = (const float*)d_in[2];
  const float* bih1f = (const float*)d_in[3];
  const float* bhh1f = (const float*)d_in[4];
  const float* wih1b = (const float*)d_in[5];
  const float* whh1b = (const float*)d_in[6];
  const float* bih1b = (const float*)d_in[7];
  const float* bhh1b = (const float*)d_in[8];
  const float* wih2f = (const float*)d_in[9];
  const float* whh2f = (const float*)d_in[10];
  const float* bih2f = (const float*)d_in[11];
  const float* bhh2f = (const float*)d_in[12];
  const float* wih2b = (const float*)d_in[13];
  const float* whh2b = (const float*)d_in[14];
  const float* bih2b = (const float*)d_in[15];
  const float* bhh2b = (const float*)d_in[16];
  const float* fc1w  = (const float*)d_in[17];
  const float* fc1b  = (const float*)d_in[18];
  const float* fc2w  = (const float*)d_in[19];
  const float* fc2b  = (const float*)d_in[20];
  float* out = (float*)d_out;

  // workspace (halfs): pooled_g 8,388,608 | h1out 41,943,040 (tiled) |
  //                    wswz1 327,680 | wswz2 393,216 | wfc 32,768 | biasc f32
  if (ws_size < (size_t)169287680) return;
  _Float16* pooled_g = (_Float16*)d_ws;          // [16384][512]
  _Float16* h1out = pooled_g + (size_t)8388608;  // [1024 rt][10][8][512]
  _Float16* wswz1 = h1out + (size_t)41943040;
  _Float16* wswz2 = wswz1 + 327680;
  _Float16* wfc   = wswz2 + 393216;
  float* biasc    = (float*)(wfc + 32768);

  prep_kernel<<<2952, 256, 0, stream>>>(
      wih1f, whh1f, bih1f, bhh1f, wih1b, whh1b, bih1b, bhh1b,
      wih2f, whh2f, bih2f, bhh2f, wih2b, whh2b, bih2b, bhh2b, fc1w,
      wswz1, wswz2, wfc, biasc);
  lstm_kernel<1><<<dim3(512, 2), 512, 0, stream>>>(x, wswz1, biasc, h1out);
  lstm_kernel<2><<<dim3(512, 2), 512, 0, stream>>>(h1out, wswz2, biasc + 1024, pooled_g);
  fc_kernel<<<256, 256, 0, stream>>>(pooled_g, wfc, fc1b, fc2w, fc2b, out);
}